// Round 4
// baseline (425.409 us; speedup 1.0000x reference)
//
#include <hip/hip_runtime.h>
#include <math.h>

#define D   1024
#define H   16
#define HD  64
#define SEQ 2048
#define LL  8
#define QKV_LD 3072
#define SCALE 0.125f

typedef __attribute__((ext_vector_type(8))) __bf16 bf16x8;
typedef __attribute__((ext_vector_type(4))) float floatx4;
typedef __attribute__((ext_vector_type(8))) unsigned short ushort8;

__device__ inline unsigned short f32_to_bf16(float f) {
    unsigned int u = __builtin_bit_cast(unsigned int, f);
    u += 0x7FFF + ((u >> 16) & 1);   // round-to-nearest-even
    return (unsigned short)(u >> 16);
}
__device__ inline float bf2f(unsigned short u) {
    unsigned int x = (unsigned int)u << 16;
    return __builtin_bit_cast(float, x);
}
__device__ inline void load_lds16(const void* g, void* l) {
    __builtin_amdgcn_global_load_lds(
        (__attribute__((address_space(1))) void*)g,
        (__attribute__((address_space(3))) void*)l, 16, 0, 0);
}

// XCD-aware swizzle: each XCD gets a contiguous chunk of the flattened grid,
// so blocks sharing an A-row-panel (consecutive bx at fixed by) run on the
// SAME XCD and hit its L2. Requires gridDim.x*gridDim.y % 8 == 0.
__device__ inline void xcd_swizzle(int& bx, int& by) {
    const int gx   = gridDim.x;
    const int lin  = blockIdx.y * gx + blockIdx.x;
    const int nblk = gx * gridDim.y;
    const int virt = (lin & 7) * (nblk >> 3) + (lin >> 3);
    bx = virt % gx;
    by = virt / gx;
}

// ---------------------------------------------------------------------------
// fused f32 -> bf16 convert for x, Wqkv, Wcol, Wout (quad counts hardcoded)
// ---------------------------------------------------------------------------
#define NQ_X    524288
#define NQ_WQKV 786432
#define NQ_WC   262144
#define NQ_WO   262144
__global__ __launch_bounds__(256) void cvt_all_kernel(
    const float* __restrict__ x, const float* __restrict__ Wqkv,
    const float* __restrict__ Wcol, const float* __restrict__ Wout,
    unsigned short* __restrict__ xb, unsigned short* __restrict__ Wqkvb,
    unsigned short* __restrict__ Wcolb, unsigned short* __restrict__ Woutb)
{
    int i = blockIdx.x * 256 + threadIdx.x;
    const float* src; unsigned short* dst; int off;
    if (i < NQ_X)                          { src = x;    dst = xb;    off = i; }
    else if (i < NQ_X + NQ_WQKV)           { src = Wqkv; dst = Wqkvb; off = i - NQ_X; }
    else if (i < NQ_X + NQ_WQKV + NQ_WC)   { src = Wcol; dst = Wcolb; off = i - NQ_X - NQ_WQKV; }
    else                                   { src = Wout; dst = Woutb; off = i - NQ_X - NQ_WQKV - NQ_WC; }
    float4 v = ((const float4*)src)[off];
    ushort4 o;
    o.x = f32_to_bf16(v.x); o.y = f32_to_bf16(v.y);
    o.z = f32_to_bf16(v.z); o.w = f32_to_bf16(v.w);
    ((ushort4*)dst)[off] = o;
}

// ---------------------------------------------------------------------------
// bf16 MFMA GEMM: C[M,N] = A[M,K] @ W[N,K]^T + bias[N]. CT = float or ushort.
// 128x128 tile, BK=32, 4 waves, 4x4 16x16x32 MFMAs per wave. XCD-swizzled.
// ---------------------------------------------------------------------------
template <typename CT>
__global__ __launch_bounds__(256) void gemm_bf16_kernel(
    const unsigned short* __restrict__ A, const unsigned short* __restrict__ W,
    const float* __restrict__ bias, CT* __restrict__ C, int K, int N)
{
    __shared__ unsigned short As[128 * 32];
    __shared__ unsigned short Ws[128 * 32];
    const int t    = threadIdx.x;
    const int wave = t >> 6, lane = t & 63;
    const int wm   = wave >> 1, wn = wave & 1;
    int bx, by;
    xcd_swizzle(bx, by);
    const int m0 = by * 128, n0 = bx * 128;

    floatx4 acc[4][4];
#pragma unroll
    for (int i = 0; i < 4; i++)
#pragma unroll
        for (int j = 0; j < 4; j++) acc[i][j] = (floatx4)0.f;

    const int lrow = lane >> 2;
    const int lcol = (lane & 3) * 8;
    const unsigned short* Ag = A + (size_t)(m0 + wave * 32 + lrow) * K + lcol;
    const unsigned short* Wg = W + (size_t)(n0 + wave * 32 + lrow) * K + lcol;
    unsigned short* Asw = &As[wave * 32 * 32];
    unsigned short* Wsw = &Ws[wave * 32 * 32];
    const size_t rowskip = (size_t)16 * K;

    const int arow  = lane & 15;
    const int aquad = (lane >> 4) * 8;

    for (int k0 = 0; k0 < K; k0 += 32) {
        load_lds16(Ag + k0,           Asw);
        load_lds16(Ag + k0 + rowskip, Asw + 16 * 32);
        load_lds16(Wg + k0,           Wsw);
        load_lds16(Wg + k0 + rowskip, Wsw + 16 * 32);
        __syncthreads();

        bf16x8 af[4], wf[4];
#pragma unroll
        for (int mi = 0; mi < 4; mi++)
            af[mi] = *(const bf16x8*)&As[(wm * 64 + mi * 16 + arow) * 32 + aquad];
#pragma unroll
        for (int ni = 0; ni < 4; ni++)
            wf[ni] = *(const bf16x8*)&Ws[(wn * 64 + ni * 16 + arow) * 32 + aquad];
#pragma unroll
        for (int mi = 0; mi < 4; mi++)
#pragma unroll
            for (int ni = 0; ni < 4; ni++)
                acc[mi][ni] = __builtin_amdgcn_mfma_f32_16x16x32_bf16(
                    af[mi], wf[ni], acc[mi][ni], 0, 0, 0);
        __syncthreads();
    }

    const int crow = (lane >> 4) * 4, ccol = lane & 15;
#pragma unroll
    for (int mi = 0; mi < 4; mi++) {
#pragma unroll
        for (int ni = 0; ni < 4; ni++) {
            const int gm = m0 + wm * 64 + mi * 16 + crow;
            const int gn = n0 + wn * 64 + ni * 16 + ccol;
            const float bb = bias[gn];
#pragma unroll
            for (int r = 0; r < 4; r++) {
                float v = acc[mi][ni][r] + bb;
                if constexpr (sizeof(CT) == 2)
                    C[(size_t)(gm + r) * N + gn] = (CT)f32_to_bf16(v);
                else
                    C[(size_t)(gm + r) * N + gn] = v;
            }
        }
    }
}

// ---------------------------------------------------------------------------
// LayerNorm of reprojected past_values -> bf16.
// ---------------------------------------------------------------------------
__global__ __launch_bounds__(256) void ln_kernel(
    const float* __restrict__ pv, unsigned short* __restrict__ ri)
{
    const int r = blockIdx.x;
    const int s = r >> 3, l = r & 7;
    const int t = threadIdx.x;
    const int h = t >> 4, e = (t & 15) * 4;
    const size_t src = (size_t)l * (H * SEQ * HD) + (size_t)h * (SEQ * HD)
                     + (size_t)s * HD + e;
    float4 v = *(const float4*)(pv + src);
    float sum = v.x + v.y + v.z + v.w;
    float sq  = v.x * v.x + v.y * v.y + v.z * v.z + v.w * v.w;
#pragma unroll
    for (int off = 32; off; off >>= 1) {
        sum += __shfl_xor(sum, off);
        sq  += __shfl_xor(sq, off);
    }
    __shared__ float red[8];
    if ((t & 63) == 0) { red[(t >> 6) * 2] = sum; red[(t >> 6) * 2 + 1] = sq; }
    __syncthreads();
    sum = red[0] + red[2] + red[4] + red[6];
    sq  = red[1] + red[3] + red[5] + red[7];
    const float mean = sum * (1.f / 1024.f);
    const float var  = sq * (1.f / 1024.f) - mean * mean;
    const float rstd = rsqrtf(var + 1e-5f);
    ushort4 o;
    o.x = f32_to_bf16((v.x - mean) * rstd);
    o.y = f32_to_bf16((v.y - mean) * rstd);
    o.z = f32_to_bf16((v.z - mean) * rstd);
    o.w = f32_to_bf16((v.w - mean) * rstd);
    *(ushort4*)(ri + (size_t)r * D + t * 4) = o;
}

// ---------------------------------------------------------------------------
// MFMA flash dual attention. Block = (head, 64-query tile), 4 waves.
// XCD-swizzled so each XCD owns 2 heads (K/V L2-resident) with heavy/light
// q-tile interleave for balance. P stored bf16 (direct A-frag reads).
// O spilled f32 into a union over the dead Q/K tiles. LDS ~39 KB -> 4 blk/CU.
// ---------------------------------------------------------------------------
union AttnShared {
    struct { unsigned short Qs[64 * 72]; unsigned short Ks[64 * 72]; } qk;
    float Osp[64 * 68];   // 17408 B <= 18432 B
};

__global__ __launch_bounds__(256) void attn_mfma_kernel(
    const unsigned short* __restrict__ qkv, const unsigned short* __restrict__ qcol,
    const unsigned short* __restrict__ rkv, unsigned short* __restrict__ ctx)
{
    const int t    = threadIdx.x;
    const int w    = t >> 6, lane = t & 63;
    const int lrow = lane & 15;          // fragment m/n index
    const int lk   = (lane >> 4) * 8;    // fragment k offset
    const int rrow = (lane >> 4) * 4;    // C/D row base
    // swizzle: 512 blocks -> xcd = lin&7 owns heads [2*xcd, 2*xcd+2)
    const int lin  = blockIdx.y * 32 + blockIdx.x;
    const int slot = lin >> 3;                       // 0..63
    const int h    = (lin & 7) * 2 + (slot >> 5);
    const int loc  = slot & 31;
    const int qt   = (loc & 1) ? (31 - (loc >> 1)) : (loc >> 1);
    const int q0   = qt * 64;

    __shared__ AttnShared U;
    __shared__ unsigned short Vt[64 * 72];   // [e][key]
    __shared__ unsigned short Pb[64 * 72];   // P bf16, [q][key]
    __shared__ float row_m[64], row_l[64];
    __shared__ float mem_alpha[64], mem_suml[64], mem_p[64 * 8];

    // stage Q [q][e]
#pragma unroll
    for (int p = 0; p < 2; p++) {
        int idx = p * 256 + t;
        int row = idx >> 3, col = (idx & 7) * 8;
        *(bf16x8*)&U.qk.Qs[row * 72 + col] =
            *(const bf16x8*)(qkv + (size_t)(q0 + row) * QKV_LD + h * HD + col);
    }

    float m_i[4], l_i[4];
    floatx4 Oacc[4];
#pragma unroll
    for (int r = 0; r < 4; r++) { m_i[r] = -1e30f; l_i[r] = 0.f; }
#pragma unroll
    for (int et = 0; et < 4; et++) Oacc[et] = (floatx4)0.f;

    for (int jt = 0; jt <= qt; jt++) {
        const int j0 = jt * 64;
        // stage K [key][e]
#pragma unroll
        for (int p = 0; p < 2; p++) {
            int idx = p * 256 + t;
            int row = idx >> 3, col = (idx & 7) * 8;
            *(bf16x8*)&U.qk.Ks[row * 72 + col] =
                *(const bf16x8*)(qkv + (size_t)(j0 + row) * QKV_LD + D + h * HD + col);
        }
        // stage V transposed -> Vt[e][key]
        {
            const int pr = t & 31, eg = t >> 5;
            const unsigned short* v0 =
                qkv + (size_t)(j0 + 2 * pr) * QKV_LD + 2 * D + h * HD + eg * 8;
            ushort8 a = *(const ushort8*)v0;
            ushort8 b = *(const ushort8*)(v0 + QKV_LD);
#pragma unroll
            for (int j = 0; j < 8; j++) {
                unsigned int pk = (unsigned int)a[j] | ((unsigned int)b[j] << 16);
                *(unsigned int*)&Vt[(eg * 8 + j) * 72 + 2 * pr] = pk;
            }
        }
        __syncthreads();

        // S = Q K^T
        floatx4 S[4];
#pragma unroll
        for (int nt = 0; nt < 4; nt++) S[nt] = (floatx4)0.f;
#pragma unroll
        for (int kst = 0; kst < 2; kst++) {
            bf16x8 aq = *(const bf16x8*)&U.qk.Qs[(w * 16 + lrow) * 72 + kst * 32 + lk];
#pragma unroll
            for (int nt = 0; nt < 4; nt++) {
                bf16x8 bk = *(const bf16x8*)&U.qk.Ks[(nt * 16 + lrow) * 72 + kst * 32 + lk];
                S[nt] = __builtin_amdgcn_mfma_f32_16x16x32_bf16(aq, bk, S[nt], 0, 0, 0);
            }
        }

        // online softmax; P -> Pb (bf16)
#pragma unroll
        for (int r = 0; r < 4; r++) {
            const int qg = q0 + w * 16 + rrow + r;
            float sc[4];
            float mx = -1e30f;
#pragma unroll
            for (int nt = 0; nt < 4; nt++) {
                sc[nt] = S[nt][r] * SCALE;
                if (j0 + nt * 16 + lrow > qg) sc[nt] = -1e30f;
                mx = fmaxf(mx, sc[nt]);
            }
#pragma unroll
            for (int off = 1; off < 16; off <<= 1)
                mx = fmaxf(mx, __shfl_xor(mx, off));
            const float newm  = fmaxf(m_i[r], mx);
            const float alpha = __expf(m_i[r] - newm);
            m_i[r] = newm;
            float ps = 0.f;
#pragma unroll
            for (int nt = 0; nt < 4; nt++) {
                float pe = __expf(sc[nt] - newm);
                ps += pe;
                Pb[(w * 16 + rrow + r) * 72 + nt * 16 + lrow] = f32_to_bf16(pe);
            }
#pragma unroll
            for (int off = 1; off < 16; off <<= 1)
                ps += __shfl_xor(ps, off);
            l_i[r] = l_i[r] * alpha + ps;
#pragma unroll
            for (int et = 0; et < 4; et++) Oacc[et][r] *= alpha;
        }

        // O += P @ V  (A-frag read directly from Pb)
#pragma unroll
        for (int kst = 0; kst < 2; kst++) {
            bf16x8 ap = *(const bf16x8*)&Pb[(w * 16 + lrow) * 72 + kst * 32 + lk];
#pragma unroll
            for (int et = 0; et < 4; et++) {
                bf16x8 bv = *(const bf16x8*)&Vt[(et * 16 + lrow) * 72 + kst * 32 + lk];
                Oacc[et] = __builtin_amdgcn_mfma_f32_16x16x32_bf16(ap, bv, Oacc[et], 0, 0, 0);
            }
        }
        __syncthreads();
    }

    // ---- spill O (f32), m, l ----
#pragma unroll
    for (int r = 0; r < 4; r++) {
        const int ql = w * 16 + rrow + r;
        if (lrow == 0) { row_m[ql] = m_i[r]; row_l[ql] = l_i[r]; }
#pragma unroll
        for (int et = 0; et < 4; et++)
            U.Osp[ql * 68 + et * 16 + lrow] = Oacc[et][r];
    }
    __syncthreads();

    // ---- memory-key scores ----
    {
        const int qi = t >> 2, quad = t & 3;
        const int qg = q0 + qi;
        float qv[16];
        const unsigned short* qcp = qcol + (size_t)qg * D + h * HD + quad * 16;
        ushort8 qa = *(const ushort8*)qcp;
        ushort8 qb = *(const ushort8*)(qcp + 8);
#pragma unroll
        for (int j = 0; j < 8; j++) {
            qv[j]     = bf2f(qa[j]) * SCALE;
            qv[8 + j] = bf2f(qb[j]) * SCALE;
        }
        float ms[8];
#pragma unroll
        for (int l = 0; l < 8; l++) {
            const unsigned short* rr = rkv + (size_t)(qg * LL + l) * 2048 + h * HD + quad * 16;
            ushort8 ra = *(const ushort8*)rr;
            ushort8 rb = *(const ushort8*)(rr + 8);
            float pacc = 0.f;
#pragma unroll
            for (int j = 0; j < 8; j++)
                pacc += qv[j] * bf2f(ra[j]) + qv[8 + j] * bf2f(rb[j]);
            pacc += __shfl_xor(pacc, 1);
            pacc += __shfl_xor(pacc, 2);
            ms[l] = pacc;
        }
        const float mo = row_m[qi];
        float mm = mo;
#pragma unroll
        for (int l = 0; l < 8; l++) mm = fmaxf(mm, ms[l]);
        const float alpha = __expf(mo - mm);
        float suml = 0.f;
        float pl[8];
#pragma unroll
        for (int l = 0; l < 8; l++) { pl[l] = __expf(ms[l] - mm); suml += pl[l]; }
        if (quad == 0) {
            mem_alpha[qi] = alpha;
            mem_suml[qi]  = suml;
#pragma unroll
            for (int l = 0; l < 8; l++) mem_p[qi * 8 + l] = pl[l];
        }
    }
    __syncthreads();

    // ---- combine + write ctx (bf16) ----
    {
        const int tx = t & 15, ty = t >> 4;
#pragma unroll
        for (int i = 0; i < 4; i++) {
            const int qi = ty * 4 + i, qg = q0 + qi;
            const float alpha = mem_alpha[qi];
            const float lf = row_l[qi] * alpha + mem_suml[qi];
            float4 o = *(const float4*)&U.Osp[qi * 68 + tx * 4];
            o.x *= alpha; o.y *= alpha; o.z *= alpha; o.w *= alpha;
#pragma unroll
            for (int l = 0; l < 8; l++) {
                const float p = mem_p[qi * 8 + l];
                ushort4 vb = *(const ushort4*)(rkv + (size_t)(qg * LL + l) * 2048
                                               + D + h * HD + tx * 4);
                o.x = fmaf(p, bf2f(vb.x), o.x);
                o.y = fmaf(p, bf2f(vb.y), o.y);
                o.z = fmaf(p, bf2f(vb.z), o.z);
                o.w = fmaf(p, bf2f(vb.w), o.w);
            }
            const float rr = 1.f / lf;
            ushort4 ob;
            ob.x = f32_to_bf16(o.x * rr); ob.y = f32_to_bf16(o.y * rr);
            ob.z = f32_to_bf16(o.z * rr); ob.w = f32_to_bf16(o.w * rr);
            *(ushort4*)(ctx + (size_t)qg * D + h * HD + tx * 4) = ob;
        }
    }
}

// ---------------------------------------------------------------------------
extern "C" void kernel_launch(void* const* d_in, const int* in_sizes, int n_in,
                              void* d_out, int out_size, void* d_ws, size_t ws_size,
                              hipStream_t stream)
{
    const float* x    = (const float*)d_in[0];
    const float* pv   = (const float*)d_in[1];
    const float* Wqkv = (const float*)d_in[2];
    const float* bqkv = (const float*)d_in[3];
    const float* Wcol = (const float*)d_in[4];
    const float* bcol = (const float*)d_in[5];
    const float* Wout = (const float*)d_in[6];
    const float* bout = (const float*)d_in[7];
    float* out = (float*)d_out;

    char* p = (char*)d_ws;
    unsigned short* x_bf    = (unsigned short*)p; p += (size_t)2048 * 1024 * 2;
    unsigned short* Wqkv_bf = (unsigned short*)p; p += (size_t)3072 * 1024 * 2;
    unsigned short* Wcol_bf = (unsigned short*)p; p += (size_t)1024 * 1024 * 2;
    unsigned short* Wout_bf = (unsigned short*)p; p += (size_t)1024 * 1024 * 2;
    unsigned short* ri_bf   = (unsigned short*)p; p += (size_t)16384 * 1024 * 2;
    unsigned short* qkv_bf  = (unsigned short*)p; p += (size_t)2048 * 3072 * 2;
    unsigned short* qcol_bf = (unsigned short*)p; p += (size_t)2048 * 1024 * 2;
    unsigned short* rkv_bf  = (unsigned short*)p; p += (size_t)16384 * 2048 * 2;
    unsigned short* ctx_bf  = (unsigned short*)p; p += (size_t)2048 * 1024 * 2;

    cvt_all_kernel<<<7168, 256, 0, stream>>>(x, Wqkv, Wcol, Wout,
                                             x_bf, Wqkv_bf, Wcol_bf, Wout_bf);
    ln_kernel<<<16384, 256, 0, stream>>>(pv, ri_bf);

    // qkv = x @ Wqkv^T + bqkv  (bf16 out)
    gemm_bf16_kernel<unsigned short><<<dim3(24, 16), 256, 0, stream>>>(
        x_bf, Wqkv_bf, bqkv, qkv_bf, 1024, 3072);
    // q_col = x @ Wcol^T + bcol  (bf16 out)
    gemm_bf16_kernel<unsigned short><<<dim3(8, 16), 256, 0, stream>>>(
        x_bf, Wcol_bf, bcol, qcol_bf, 1024, 1024);
    // rkv = ri @ Wqkv[1024:3072]^T + bqkv[1024:3072]  (bf16 out)
    gemm_bf16_kernel<unsigned short><<<dim3(16, 128), 256, 0, stream>>>(
        ri_bf, Wqkv_bf + (size_t)1024 * 1024, bqkv + 1024, rkv_bf, 1024, 2048);
    // attention -> ctx (bf16)
    attn_mfma_kernel<<<dim3(32, 16), 256, 0, stream>>>(qkv_bf, qcol_bf, rkv_bf, ctx_bf);
    // out = ctx @ Wout^T + bout  (f32 out)
    gemm_bf16_kernel<float><<<dim3(8, 16), 256, 0, stream>>>(
        ctx_bf, Wout_bf, bout, out, 1024, 1024);
}

// Round 5
// 363.430 us; speedup vs baseline: 1.1705x; 1.1705x over previous
//
#include <hip/hip_runtime.h>
#include <math.h>

#define D   1024
#define H   16
#define HD  64
#define SEQ 2048
#define LL  8
#define SCALE 0.125f

typedef __attribute__((ext_vector_type(8))) __bf16 bf16x8;
typedef __attribute__((ext_vector_type(4))) float floatx4;
typedef __attribute__((ext_vector_type(8))) unsigned short ushort8;

__device__ inline unsigned short f32_to_bf16(float f) {
    unsigned int u = __builtin_bit_cast(unsigned int, f);
    u += 0x7FFF + ((u >> 16) & 1);   // round-to-nearest-even
    return (unsigned short)(u >> 16);
}
__device__ inline float bf2f(unsigned short u) {
    unsigned int x = (unsigned int)u << 16;
    return __builtin_bit_cast(float, x);
}
__device__ inline void load_lds16(const void* g, void* l) {
    __builtin_amdgcn_global_load_lds(
        (__attribute__((address_space(1))) void*)g,
        (__attribute__((address_space(3))) void*)l, 16, 0, 0);
}

// XCD-aware swizzle: contiguous grid chunk per XCD -> A-panel L2 reuse.
__device__ inline void xcd_swizzle(int& bx, int& by) {
    const int gx   = gridDim.x;
    const int lin  = blockIdx.y * gx + blockIdx.x;
    const int nblk = gx * gridDim.y;
    const int virt = (lin & 7) * (nblk >> 3) + (lin >> 3);
    bx = virt % gx;
    by = virt / gx;
}

// ---------------------------------------------------------------------------
// prep: LN(reproject(pv)) -> ri_bf  |  f32->bf16 of x, Wqkv|Wcol (->W4), Wout
//       |  bias concat b4 = [bqkv, bcol]
// ---------------------------------------------------------------------------
#define NQ_X    524288
#define NQ_WQKV 786432
#define NQ_WC   262144
#define NQ_WO   262144
#define LN_BLK  16384
#define CVT_BLK 7168          // (NQ_X+NQ_WQKV+NQ_WC+NQ_WO)/256
#define PREP_GRID (LN_BLK + CVT_BLK + 4)

__global__ __launch_bounds__(256) void prep_kernel(
    const float* __restrict__ pv, const float* __restrict__ x,
    const float* __restrict__ Wqkv, const float* __restrict__ Wcol,
    const float* __restrict__ Wout, const float* __restrict__ bqkv,
    const float* __restrict__ bcol,
    unsigned short* __restrict__ ri, unsigned short* __restrict__ xb,
    unsigned short* __restrict__ W4b, unsigned short* __restrict__ Woutb,
    float* __restrict__ b4)
{
    const int b = blockIdx.x;
    const int t = threadIdx.x;
    if (b < LN_BLK) {
        // LayerNorm row r = s*L + l over d=1024
        const int r = b;
        const int s = r >> 3, l = r & 7;
        const int h = t >> 4, e = (t & 15) * 4;
        const size_t src = (size_t)l * (H * SEQ * HD) + (size_t)h * (SEQ * HD)
                         + (size_t)s * HD + e;
        float4 v = *(const float4*)(pv + src);
        float sum = v.x + v.y + v.z + v.w;
        float sq  = v.x * v.x + v.y * v.y + v.z * v.z + v.w * v.w;
#pragma unroll
        for (int off = 32; off; off >>= 1) {
            sum += __shfl_xor(sum, off);
            sq  += __shfl_xor(sq, off);
        }
        __shared__ float red[8];
        if ((t & 63) == 0) { red[(t >> 6) * 2] = sum; red[(t >> 6) * 2 + 1] = sq; }
        __syncthreads();
        sum = red[0] + red[2] + red[4] + red[6];
        sq  = red[1] + red[3] + red[5] + red[7];
        const float mean = sum * (1.f / 1024.f);
        const float var  = sq * (1.f / 1024.f) - mean * mean;
        const float rstd = rsqrtf(var + 1e-5f);
        ushort4 o;
        o.x = f32_to_bf16((v.x - mean) * rstd);
        o.y = f32_to_bf16((v.y - mean) * rstd);
        o.z = f32_to_bf16((v.z - mean) * rstd);
        o.w = f32_to_bf16((v.w - mean) * rstd);
        *(ushort4*)(ri + (size_t)r * D + t * 4) = o;
    } else if (b < LN_BLK + CVT_BLK) {
        const int i = (b - LN_BLK) * 256 + t;
        const float* src; unsigned short* dst; int off;
        if (i < NQ_X)                        { src = x;    dst = xb;    off = i; }
        else if (i < NQ_X + NQ_WQKV)         { src = Wqkv; dst = W4b;   off = i - NQ_X; }
        else if (i < NQ_X + NQ_WQKV + NQ_WC) { src = Wcol; dst = W4b;   off = i - NQ_X;     // Wcol lands right after Wqkv in W4
                                               src = Wcol; off = i - NQ_X - NQ_WQKV;
                                               dst = W4b + (size_t)NQ_WQKV * 4 / 1; // quads->elements below
                                               // handled explicitly below
                                               {
                                                   float4 v = ((const float4*)Wcol)[i - NQ_X - NQ_WQKV];
                                                   ushort4 o;
                                                   o.x = f32_to_bf16(v.x); o.y = f32_to_bf16(v.y);
                                                   o.z = f32_to_bf16(v.z); o.w = f32_to_bf16(v.w);
                                                   ((ushort4*)(W4b))[NQ_WQKV + (i - NQ_X - NQ_WQKV)] = o;
                                               }
                                               return; }
        else                                 { src = Wout; dst = Woutb; off = i - NQ_X - NQ_WQKV - NQ_WC; }
        float4 v = ((const float4*)src)[off];
        ushort4 o;
        o.x = f32_to_bf16(v.x); o.y = f32_to_bf16(v.y);
        o.z = f32_to_bf16(v.z); o.w = f32_to_bf16(v.w);
        ((ushort4*)dst)[off] = o;
    } else {
        // bias concat: 1024 float4 quads, first 768 from bqkv, rest from bcol
        const int q = (b - LN_BLK - CVT_BLK) * 256 + t;
        float4 v = (q < 768) ? ((const float4*)bqkv)[q] : ((const float4*)bcol)[q - 768];
        ((float4*)b4)[q] = v;
    }
}

// ---------------------------------------------------------------------------
// bf16 MFMA GEMM: C[M,N] = A[M,K] @ W[N,K]^T + bias[N]. CT = float or ushort.
// 128x128 tile, BK=32, 4 waves, 4x4 16x16x32 MFMAs per wave. XCD-swizzled.
// ---------------------------------------------------------------------------
template <typename CT>
__global__ __launch_bounds__(256) void gemm_bf16_kernel(
    const unsigned short* __restrict__ A, const unsigned short* __restrict__ W,
    const float* __restrict__ bias, CT* __restrict__ C, int K, int N)
{
    __shared__ unsigned short As[128 * 32];
    __shared__ unsigned short Ws[128 * 32];
    const int t    = threadIdx.x;
    const int wave = t >> 6, lane = t & 63;
    const int wm   = wave >> 1, wn = wave & 1;
    int bx, by;
    xcd_swizzle(bx, by);
    const int m0 = by * 128, n0 = bx * 128;

    floatx4 acc[4][4];
#pragma unroll
    for (int i = 0; i < 4; i++)
#pragma unroll
        for (int j = 0; j < 4; j++) acc[i][j] = (floatx4)0.f;

    const int lrow = lane >> 2;
    const int lcol = (lane & 3) * 8;
    const unsigned short* Ag = A + (size_t)(m0 + wave * 32 + lrow) * K + lcol;
    const unsigned short* Wg = W + (size_t)(n0 + wave * 32 + lrow) * K + lcol;
    unsigned short* Asw = &As[wave * 32 * 32];
    unsigned short* Wsw = &Ws[wave * 32 * 32];
    const size_t rowskip = (size_t)16 * K;

    const int arow  = lane & 15;
    const int aquad = (lane >> 4) * 8;

    for (int k0 = 0; k0 < K; k0 += 32) {
        load_lds16(Ag + k0,           Asw);
        load_lds16(Ag + k0 + rowskip, Asw + 16 * 32);
        load_lds16(Wg + k0,           Wsw);
        load_lds16(Wg + k0 + rowskip, Wsw + 16 * 32);
        __syncthreads();

        bf16x8 af[4], wf[4];
#pragma unroll
        for (int mi = 0; mi < 4; mi++)
            af[mi] = *(const bf16x8*)&As[(wm * 64 + mi * 16 + arow) * 32 + aquad];
#pragma unroll
        for (int ni = 0; ni < 4; ni++)
            wf[ni] = *(const bf16x8*)&Ws[(wn * 64 + ni * 16 + arow) * 32 + aquad];
#pragma unroll
        for (int mi = 0; mi < 4; mi++)
#pragma unroll
            for (int ni = 0; ni < 4; ni++)
                acc[mi][ni] = __builtin_amdgcn_mfma_f32_16x16x32_bf16(
                    af[mi], wf[ni], acc[mi][ni], 0, 0, 0);
        __syncthreads();
    }

    const int crow = (lane >> 4) * 4, ccol = lane & 15;
#pragma unroll
    for (int mi = 0; mi < 4; mi++) {
#pragma unroll
        for (int ni = 0; ni < 4; ni++) {
            const int gm = m0 + wm * 64 + mi * 16 + crow;
            const int gn = n0 + wn * 64 + ni * 16 + ccol;
            const float bb = bias[gn];
#pragma unroll
            for (int r = 0; r < 4; r++) {
                float v = acc[mi][ni][r] + bb;
                if constexpr (sizeof(CT) == 2)
                    C[(size_t)(gm + r) * N + gn] = (CT)f32_to_bf16(v);
                else
                    C[(size_t)(gm + r) * N + gn] = v;
            }
        }
    }
}

// ---------------------------------------------------------------------------
// Split-K MFMA flash dual attention.
// Grid = 1024 blocks = 16 heads x 32 q-tiles x 2 key-splits; 4 blocks/CU,
// all co-resident. qt quadruples {a,15-a,16+a,31-a} per CU -> balanced work.
// Split 0 also folds the 8 memory keys. Partials (O,m,l) -> workspace.
// qkv4 is the fused [2048][4096] Q|K|V|Qcol tensor.
// ---------------------------------------------------------------------------
union AttnShared {
    struct { unsigned short Qs[64 * 72]; unsigned short Ks[64 * 72]; } qk;
    float Osp[64 * 68];
};

__global__ __launch_bounds__(256) void attn_split_kernel(
    const unsigned short* __restrict__ qkv4, const unsigned short* __restrict__ rkv,
    float* __restrict__ Opart, float2* __restrict__ mlpart)
{
    const int t    = threadIdx.x;
    const int w    = t >> 6, lane = t & 63;
    const int lrow = lane & 15;
    const int lk   = (lane >> 4) * 8;
    const int rrow = (lane >> 4) * 4;
    const int lin  = blockIdx.x;
    const int hs   = lin & 31, g = lin >> 5;
    const int h    = hs >> 1, s = hs & 1;
    const int a    = g & 7, bq = g >> 3;
    const int qt   = (bq == 0) ? a : (bq == 1) ? 15 - a : (bq == 2) ? 16 + a : 31 - a;
    const int q0   = qt * 64;
    const int n    = qt + 1, nh = (n + 1) >> 1;
    const int lo   = s ? nh : 0, hi = s ? n : nh;
    const int part = (h * 32 + qt) * 2 + s;

    __shared__ AttnShared U;
    __shared__ unsigned short Vt[64 * 72];   // [e][key]
    __shared__ unsigned short Pb[64 * 72];   // P bf16 [q][key]
    __shared__ float row_m[64], row_l[64];
    __shared__ float mem_mm[64], mem_alpha[64], mem_suml[64], mem_p[64 * 8];

    // stage Q [q][e]
#pragma unroll
    for (int p = 0; p < 2; p++) {
        int idx = p * 256 + t;
        int row = idx >> 3, col = (idx & 7) * 8;
        *(bf16x8*)&U.qk.Qs[row * 72 + col] =
            *(const bf16x8*)(qkv4 + (size_t)(q0 + row) * 4096 + h * HD + col);
    }

    float m_i[4], l_i[4];
    floatx4 Oacc[4];
#pragma unroll
    for (int r = 0; r < 4; r++) { m_i[r] = -1e30f; l_i[r] = 0.f; }
#pragma unroll
    for (int et = 0; et < 4; et++) Oacc[et] = (floatx4)0.f;

    for (int jt = lo; jt < hi; jt++) {
        const int j0 = jt * 64;
        // stage K [key][e]
#pragma unroll
        for (int p = 0; p < 2; p++) {
            int idx = p * 256 + t;
            int row = idx >> 3, col = (idx & 7) * 8;
            *(bf16x8*)&U.qk.Ks[row * 72 + col] =
                *(const bf16x8*)(qkv4 + (size_t)(j0 + row) * 4096 + D + h * HD + col);
        }
        // stage V transposed -> Vt[e][key]
        {
            const int pr = t & 31, eg = t >> 5;
            const unsigned short* v0 =
                qkv4 + (size_t)(j0 + 2 * pr) * 4096 + 2 * D + h * HD + eg * 8;
            ushort8 va = *(const ushort8*)v0;
            ushort8 vb = *(const ushort8*)(v0 + 4096);
#pragma unroll
            for (int j = 0; j < 8; j++) {
                unsigned int pk = (unsigned int)va[j] | ((unsigned int)vb[j] << 16);
                *(unsigned int*)&Vt[(eg * 8 + j) * 72 + 2 * pr] = pk;
            }
        }
        __syncthreads();

        // S = Q K^T
        floatx4 S[4];
#pragma unroll
        for (int nt = 0; nt < 4; nt++) S[nt] = (floatx4)0.f;
#pragma unroll
        for (int kst = 0; kst < 2; kst++) {
            bf16x8 aq = *(const bf16x8*)&U.qk.Qs[(w * 16 + lrow) * 72 + kst * 32 + lk];
#pragma unroll
            for (int nt = 0; nt < 4; nt++) {
                bf16x8 bk = *(const bf16x8*)&U.qk.Ks[(nt * 16 + lrow) * 72 + kst * 32 + lk];
                S[nt] = __builtin_amdgcn_mfma_f32_16x16x32_bf16(aq, bk, S[nt], 0, 0, 0);
            }
        }

        // online softmax; P -> Pb (bf16)
#pragma unroll
        for (int r = 0; r < 4; r++) {
            const int qg = q0 + w * 16 + rrow + r;
            float sc[4];
            float mx = -1e30f;
#pragma unroll
            for (int nt = 0; nt < 4; nt++) {
                sc[nt] = S[nt][r] * SCALE;
                if (j0 + nt * 16 + lrow > qg) sc[nt] = -1e30f;
                mx = fmaxf(mx, sc[nt]);
            }
#pragma unroll
            for (int off = 1; off < 16; off <<= 1)
                mx = fmaxf(mx, __shfl_xor(mx, off));
            if (mx <= -1e29f) {
                // entire tile masked for this row (split-1 early rows)
#pragma unroll
                for (int nt = 0; nt < 4; nt++)
                    Pb[(w * 16 + rrow + r) * 72 + nt * 16 + lrow] = 0;
                continue;
            }
            const float newm  = fmaxf(m_i[r], mx);
            const float alpha = __expf(m_i[r] - newm);
            m_i[r] = newm;
            float ps = 0.f;
#pragma unroll
            for (int nt = 0; nt < 4; nt++) {
                float pe = __expf(sc[nt] - newm);
                ps += pe;
                Pb[(w * 16 + rrow + r) * 72 + nt * 16 + lrow] = f32_to_bf16(pe);
            }
#pragma unroll
            for (int off = 1; off < 16; off <<= 1)
                ps += __shfl_xor(ps, off);
            l_i[r] = l_i[r] * alpha + ps;
#pragma unroll
            for (int et = 0; et < 4; et++) Oacc[et][r] *= alpha;
        }
        __syncthreads();

        // O += P @ V
#pragma unroll
        for (int kst = 0; kst < 2; kst++) {
            bf16x8 ap = *(const bf16x8*)&Pb[(w * 16 + lrow) * 72 + kst * 32 + lk];
#pragma unroll
            for (int et = 0; et < 4; et++) {
                bf16x8 bv = *(const bf16x8*)&Vt[(et * 16 + lrow) * 72 + kst * 32 + lk];
                Oacc[et] = __builtin_amdgcn_mfma_f32_16x16x32_bf16(ap, bv, Oacc[et], 0, 0, 0);
            }
        }
        __syncthreads();
    }

    if (s == 1) {
        // write partials straight from registers
#pragma unroll
        for (int r = 0; r < 4; r++) {
            const int ql = w * 16 + rrow + r;
            if (lrow == 0) mlpart[(size_t)part * 64 + ql] = make_float2(m_i[r], l_i[r]);
#pragma unroll
            for (int et = 0; et < 4; et++)
                Opart[((size_t)part * 64 + ql) * 64 + et * 16 + lrow] = Oacc[et][r];
        }
        return;
    }

    // ---- split 0: fold memory keys, then write partials ----
#pragma unroll
    for (int r = 0; r < 4; r++) {
        const int ql = w * 16 + rrow + r;
        if (lrow == 0) { row_m[ql] = m_i[r]; row_l[ql] = l_i[r]; }
#pragma unroll
        for (int et = 0; et < 4; et++)
            U.Osp[ql * 68 + et * 16 + lrow] = Oacc[et][r];
    }
    __syncthreads();

    {
        const int qi = t >> 2, quad = t & 3;
        const int qg = q0 + qi;
        float qv[16];
        const unsigned short* qcp = qkv4 + (size_t)qg * 4096 + 3 * D + h * HD + quad * 16;
        ushort8 qa = *(const ushort8*)qcp;
        ushort8 qb = *(const ushort8*)(qcp + 8);
#pragma unroll
        for (int j = 0; j < 8; j++) {
            qv[j]     = bf2f(qa[j]) * SCALE;
            qv[8 + j] = bf2f(qb[j]) * SCALE;
        }
        float ms[8];
#pragma unroll
        for (int l = 0; l < 8; l++) {
            const unsigned short* rr = rkv + (size_t)(qg * LL + l) * 2048 + h * HD + quad * 16;
            ushort8 ra = *(const ushort8*)rr;
            ushort8 rb = *(const ushort8*)(rr + 8);
            float pacc = 0.f;
#pragma unroll
            for (int j = 0; j < 8; j++)
                pacc += qv[j] * bf2f(ra[j]) + qv[8 + j] * bf2f(rb[j]);
            pacc += __shfl_xor(pacc, 1);
            pacc += __shfl_xor(pacc, 2);
            ms[l] = pacc;
        }
        const float mo = row_m[qi];
        float mm = mo;
#pragma unroll
        for (int l = 0; l < 8; l++) mm = fmaxf(mm, ms[l]);
        const float alpha = __expf(mo - mm);
        float suml = 0.f;
        float pl[8];
#pragma unroll
        for (int l = 0; l < 8; l++) { pl[l] = __expf(ms[l] - mm); suml += pl[l]; }
        if (quad == 0) {
            mem_mm[qi]    = mm;
            mem_alpha[qi] = alpha;
            mem_suml[qi]  = suml;
#pragma unroll
            for (int l = 0; l < 8; l++) mem_p[qi * 8 + l] = pl[l];
        }
    }
    __syncthreads();

    {
        const int tx = t & 15, ty = t >> 4;
#pragma unroll
        for (int i = 0; i < 4; i++) {
            const int qi = ty * 4 + i, qg = q0 + qi;
            const float alpha = mem_alpha[qi];
            const float lf = row_l[qi] * alpha + mem_suml[qi];
            float4 o = *(const float4*)&U.Osp[qi * 68 + tx * 4];
            o.x *= alpha; o.y *= alpha; o.z *= alpha; o.w *= alpha;
#pragma unroll
            for (int l = 0; l < 8; l++) {
                const float p = mem_p[qi * 8 + l];
                ushort4 vb = *(const ushort4*)(rkv + (size_t)(qg * LL + l) * 2048
                                               + D + h * HD + tx * 4);
                o.x = fmaf(p, bf2f(vb.x), o.x);
                o.y = fmaf(p, bf2f(vb.y), o.y);
                o.z = fmaf(p, bf2f(vb.z), o.z);
                o.w = fmaf(p, bf2f(vb.w), o.w);
            }
            *(float4*)&Opart[((size_t)part * 64 + qi) * 64 + tx * 4] = o;
            if (tx == 0) mlpart[(size_t)part * 64 + qi] = make_float2(mem_mm[qi], lf);
        }
    }
}

// ---------------------------------------------------------------------------
// merge: combine the two key-split partials per (h, qt), normalize, write ctx.
// ---------------------------------------------------------------------------
__global__ __launch_bounds__(256) void attn_merge_kernel(
    const float* __restrict__ Opart, const float2* __restrict__ mlpart,
    unsigned short* __restrict__ ctx)
{
    const int blk = blockIdx.x;            // h*32 + qt
    const int h = blk >> 5, qt = blk & 31;
    const int q0 = qt * 64;
    const int t = threadIdx.x, tx = t & 15, ty = t >> 4;
    const size_t p0 = (size_t)blk * 2, p1 = p0 + 1;
#pragma unroll
    for (int i = 0; i < 4; i++) {
        const int qi = ty * 4 + i, qg = q0 + qi;
        float2 ml0 = mlpart[p0 * 64 + qi];
        float2 ml1 = mlpart[p1 * 64 + qi];
        const float M  = fmaxf(ml0.x, ml1.x);
        const float f0 = __expf(ml0.x - M), f1 = __expf(ml1.x - M);
        const float rl = 1.f / (ml0.y * f0 + ml1.y * f1);
        float4 o0 = *(const float4*)&Opart[(p0 * 64 + qi) * 64 + tx * 4];
        float4 o1 = *(const float4*)&Opart[(p1 * 64 + qi) * 64 + tx * 4];
        ushort4 ob;
        ob.x = f32_to_bf16((o0.x * f0 + o1.x * f1) * rl);
        ob.y = f32_to_bf16((o0.y * f0 + o1.y * f1) * rl);
        ob.z = f32_to_bf16((o0.z * f0 + o1.z * f1) * rl);
        ob.w = f32_to_bf16((o0.w * f0 + o1.w * f1) * rl);
        *(ushort4*)(ctx + (size_t)qg * D + h * HD + tx * 4) = ob;
    }
}

// ---------------------------------------------------------------------------
extern "C" void kernel_launch(void* const* d_in, const int* in_sizes, int n_in,
                              void* d_out, int out_size, void* d_ws, size_t ws_size,
                              hipStream_t stream)
{
    const float* x    = (const float*)d_in[0];
    const float* pv   = (const float*)d_in[1];
    const float* Wqkv = (const float*)d_in[2];
    const float* bqkv = (const float*)d_in[3];
    const float* Wcol = (const float*)d_in[4];
    const float* bcol = (const float*)d_in[5];
    const float* Wout = (const float*)d_in[6];
    const float* bout = (const float*)d_in[7];
    float* out = (float*)d_out;

    char* p = (char*)d_ws;
    unsigned short* x_bf    = (unsigned short*)p; p += (size_t)2048 * 1024 * 2;
    unsigned short* W4_bf   = (unsigned short*)p; p += (size_t)4096 * 1024 * 2;   // Wqkv | Wcol
    unsigned short* Wout_bf = (unsigned short*)p; p += (size_t)1024 * 1024 * 2;
    float*          b4      = (float*)p;          p += (size_t)4096 * 4;
    unsigned short* ri_bf   = (unsigned short*)p; p += (size_t)16384 * 1024 * 2;
    unsigned short* qkv4_bf = (unsigned short*)p; p += (size_t)2048 * 4096 * 2;   // Q|K|V|Qcol
    unsigned short* rkv_bf  = (unsigned short*)p; p += (size_t)16384 * 2048 * 2;
    unsigned short* ctx_bf  = (unsigned short*)p; p += (size_t)2048 * 1024 * 2;
    float*          Opart   = (float*)p;          p += (size_t)1024 * 64 * 64 * 4;
    float2*         mlpart  = (float2*)p;         p += (size_t)1024 * 64 * 8;
    // ~153 MB total

    // LN + all bf16 casts + bias concat (1 launch)
    prep_kernel<<<PREP_GRID, 256, 0, stream>>>(pv, x, Wqkv, Wcol, Wout, bqkv, bcol,
                                               ri_bf, x_bf, W4_bf, Wout_bf, b4);
    // qkv4 = x @ [Wqkv|Wcol]^T + [bqkv|bcol]   (fused, N=4096)
    gemm_bf16_kernel<unsigned short><<<dim3(32, 16), 256, 0, stream>>>(
        x_bf, W4_bf, b4, qkv4_bf, 1024, 4096);
    // rkv = ri @ Wqkv[1024:3072]^T + bqkv[1024:3072]
    gemm_bf16_kernel<unsigned short><<<dim3(16, 128), 256, 0, stream>>>(
        ri_bf, W4_bf + (size_t)1024 * 1024, bqkv + 1024, rkv_bf, 1024, 2048);
    // attention split + merge
    attn_split_kernel<<<1024, 256, 0, stream>>>(qkv4_bf, rkv_bf, Opart, mlpart);
    attn_merge_kernel<<<512, 256, 0, stream>>>(Opart, mlpart, ctx_bf);
    // out = ctx @ Wout^T + bout
    gemm_bf16_kernel<float><<<dim3(8, 16), 256, 0, stream>>>(
        ctx_bf, Wout_bf, bout, out, 1024, 1024);
}